// Round 10
// baseline (1192.653 us; speedup 1.0000x reference)
//
#include <hip/hip_runtime.h>
#include <hip/hip_bf16.h>
#include <cstddef>
#include <type_traits>

typedef __hip_bfloat16 bf16;
typedef __attribute__((ext_vector_type(8))) short short8;   // 8 bf16 = one MFMA A/B frag
typedef __attribute__((ext_vector_type(4))) float f32x4;    // MFMA 16x16 accumulator

constexpr int H = 80, W = 96, T = 112;
constexpr int N = H * W * T;               // 860160
constexpr int WT = W * T;                  // 10752
constexpr int Hh = 40, Wh = 48, Th = 56;
constexpr int Nh = Hh * Wh * Th;
constexpr int PH = 84, PW = 100, PT = 116;
constexpr int NPF = PH * PW * PT;          // 974400

static __device__ __forceinline__ float b2f(bf16 v) { return __bfloat162float(v); }
static __device__ __forceinline__ bf16  f2b(float v) { return __float2bfloat16(v); }
static __device__ __forceinline__ float us2f(unsigned short u) { return __uint_as_float(((unsigned)u) << 16); }

// ================= weight build: w[COUT][CIN][27] f32 -> frag-order bf16 =================
__global__ __launch_bounds__(256) void wbuild_kernel(const float* __restrict__ w, bf16* __restrict__ wb,
                                                     int COUT, int CIN, int KC_TOT, int NT_TOT)
{
    int idx = blockIdx.x * 256 + threadIdx.x;
    int total = 27 * KC_TOT * NT_TOT * 512;
    if (idx >= total) return;
    int j    = idx & 7;
    int lane = (idx >> 3) & 63;
    int rest = idx >> 9;
    int nt   = rest % NT_TOT; rest /= NT_TOT;
    int kc   = rest % KC_TOT;
    int tap  = rest / KC_TOT;
    int o    = nt * 16 + (lane & 15);
    int cin  = kc * 32 + (lane >> 4) * 8 + j;
    float val = (o < COUT && cin < CIN) ? w[((size_t)o * CIN + cin) * 27 + tap] : 0.f;
    wb[idx] = f2b(val);
}

// ---- padded biases: [0,64) b1a | [64,96) b1b | [96,128) b2a | [128,160) b2b | [160,176) bf
__global__ __launch_bounds__(256) void bias_kernel(const float* __restrict__ b1a, const float* __restrict__ b1b,
                                                   const float* __restrict__ b2a, const float* __restrict__ b2b,
                                                   const float* __restrict__ bff, float* __restrict__ out)
{
    int i = threadIdx.x;
    if (i < 64)       out[i] = (i < 59) ? b1a[i] : 0.f;
    else if (i < 96)  { int j = i - 64;  out[i] = (j < 16) ? b1b[j] : 0.f; }
    else if (i < 128) { int j = i - 96;  out[i] = (j < 16) ? b2a[j] : 0.f; }
    else if (i < 160) { int j = i - 128; out[i] = (j < 16) ? b2b[j] : 0.f; }
    else if (i < 176) { int j = i - 160; out[i] = (j < 3)  ? bff[j] : 0.f; }
}

// ================= pre-conv pipeline =================
__global__ __launch_bounds__(256) void upsample_kernel(const float* __restrict__ flow,
                                                       float* __restrict__ flow_up)
{
    int idx = blockIdx.x * 256 + threadIdx.x;
    if (idx >= 3 * N) return;
    int c = idx / N, v = idx % N;
    int t = v % T; int hw = v / T; int w = hw % W; int h = hw / W;
    float ph = (float)h * ((float)(Hh - 1) / (float)(H - 1));
    float pw = (float)w * ((float)(Wh - 1) / (float)(W - 1));
    float pt = (float)t * ((float)(Th - 1) / (float)(T - 1));
    int i0 = min((int)ph, Hh - 2); float fh = ph - (float)i0;
    int j0 = min((int)pw, Wh - 2); float fw = pw - (float)j0;
    int k0 = min((int)pt, Th - 2); float ft = pt - (float)k0;
    const float* fp = flow + (size_t)c * Nh;
    auto L = [&](int a, int b, int d) -> float {
        return 2.0f * fp[((size_t)a * Wh + b) * Th + d];
    };
    float v000 = L(i0, j0, k0),     v001 = L(i0, j0, k0 + 1);
    float v010 = L(i0, j0 + 1, k0), v011 = L(i0, j0 + 1, k0 + 1);
    float v100 = L(i0 + 1, j0, k0),     v101 = L(i0 + 1, j0, k0 + 1);
    float v110 = L(i0 + 1, j0 + 1, k0), v111 = L(i0 + 1, j0 + 1, k0 + 1);
    float val = (1.f - fh) * ((1.f - fw) * ((1.f - ft) * v000 + ft * v001)
                            +        fw  * ((1.f - ft) * v010 + ft * v011))
              +        fh  * ((1.f - fw) * ((1.f - ft) * v100 + ft * v101)
                            +        fw  * ((1.f - ft) * v110 + ft * v111));
    flow_up[idx] = val;
}

// warp -> xw planar bf16 [16][N]
__global__ __launch_bounds__(256) void warp_kernel(const float* __restrict__ x,
                                                   const float* __restrict__ flow_up,
                                                   bf16* __restrict__ xw)
{
    int v = blockIdx.x * 256 + threadIdx.x;
    if (v >= N) return;
    int t = v % T; int hw = v / T; int w = hw % W; int h = hw / W;
    float cx = (float)h + flow_up[v];
    float cy = (float)w + flow_up[N + v];
    float cz = (float)t + flow_up[2 * N + v];
    float fx0 = floorf(cx), fy0 = floorf(cy), fz0 = floorf(cz);
    float fx = cx - fx0, fy = cy - fy0, fz = cz - fz0;
    int ix = (int)fx0, iy = (int)fy0, iz = (int)fz0;

    float wc[8];
    int   oc[8];
    #pragma unroll
    for (int c8 = 0; c8 < 8; c8++) {
        int dx = (c8 >> 2) & 1, dy = (c8 >> 1) & 1, dz = c8 & 1;
        int ax = ix + dx, ay = iy + dy, az = iz + dz;
        bool ok = ((unsigned)ax < (unsigned)H) && ((unsigned)ay < (unsigned)W) && ((unsigned)az < (unsigned)T);
        float wt = (dx ? fx : 1.f - fx) * (dy ? fy : 1.f - fy) * (dz ? fz : 1.f - fz);
        wc[c8] = ok ? wt : 0.f;
        int cax = min(max(ax, 0), H - 1);
        int cay = min(max(ay, 0), W - 1);
        int caz = min(max(az, 0), T - 1);
        oc[c8] = (cax * W + cay) * T + caz;
    }
    #pragma unroll 1
    for (int c = 0; c < 16; c++) {
        const float* xp = x + (size_t)c * N;
        float s = 0.f;
        #pragma unroll
        for (int c8 = 0; c8 < 8; c8++) s += wc[c8] * xp[oc[c8]];
        xw[(size_t)c * N + v] = f2b(s);
    }
}

// ===== pm = box3(xw, pad=1), strip-vectorized: 1 thread = 16 t-outputs =====
__global__ __launch_bounds__(256) void pm_kernel(const bf16* __restrict__ xw, bf16* __restrict__ pm)
{
    int idx = blockIdx.x * 256 + threadIdx.x;
    int ts = idx % 7;  int r = idx / 7;
    int w  = r % W;    r /= W;
    int h  = r % H;    int c = r / H;
    int t0 = ts * 16;

    float acc[16];
    #pragma unroll
    for (int k = 0; k < 16; k++) acc[k] = 0.f;

    const bf16* base = xw + (size_t)c * N;
    #pragma unroll
    for (int dh = -1; dh <= 1; dh++)
        #pragma unroll
        for (int dw = -1; dw <= 1; dw++) {
            int hh = h + dh, ww = w + dw;
            if (((unsigned)hh < (unsigned)H) && ((unsigned)ww < (unsigned)W)) {
                const unsigned short* rp = (const unsigned short*)(base + (size_t)(hh * W + ww) * T);
                float v[18];
                v[0] = (t0 > 0) ? us2f(rp[t0 - 1]) : 0.f;
                short8 cA = *(const short8*)(rp + t0);
                short8 cB = *(const short8*)(rp + t0 + 8);
                #pragma unroll
                for (int j = 0; j < 8; j++) v[1 + j] = us2f((unsigned short)cA[j]);
                #pragma unroll
                for (int j = 0; j < 8; j++) v[9 + j] = us2f((unsigned short)cB[j]);
                v[17] = (t0 + 16 < T) ? us2f(rp[t0 + 16]) : 0.f;
                #pragma unroll
                for (int k = 0; k < 16; k++) acc[k] += v[k] + v[k + 1] + v[k + 2];
            }
        }

    unsigned short ch[16];
    #pragma unroll
    for (int k = 0; k < 16; k++) { bf16 b = f2b(acc[k]); ch[k] = *(unsigned short*)&b; }
    uint4* dst = (uint4*)((unsigned short*)pm + (size_t)c * N + (size_t)(h * W + w) * T + t0);
    dst[0] = ((uint4*)ch)[0];
    dst[1] = ((uint4*)ch)[1];
}

// ===== pf = box3(y, pad=3), strip-vectorized: 1 thread = 16 d-outputs =====
__global__ __launch_bounds__(256) void pf_kernel(const float* __restrict__ y, bf16* __restrict__ pf)
{
    int idx = blockIdx.x * 256 + threadIdx.x;
    int ds = idx & 7;  int r = idx >> 3;
    int b  = r % PW;   r /= PW;
    int a  = r % PH;   int c = r / PH;
    int d0 = ds * 16;

    float acc[16];
    #pragma unroll
    for (int k = 0; k < 16; k++) acc[k] = 0.f;

    const float* base = y + (size_t)c * N;
    #pragma unroll
    for (int da = 0; da < 3; da++)
        #pragma unroll
        for (int db = 0; db < 3; db++) {
            int hh = a - 3 + da, ww = b - 3 + db;
            if (((unsigned)hh < (unsigned)H) && ((unsigned)ww < (unsigned)W)) {
                const float* rp = base + (size_t)(hh * W + ww) * T;
                float v[24];
                if (d0 >= 8) {
                    float4 a0 = *(const float4*)(rp + d0 - 8);
                    float4 a1 = *(const float4*)(rp + d0 - 4);
                    v[0] = a0.x; v[1] = a0.y; v[2] = a0.z; v[3] = a0.w;
                    v[4] = a1.x; v[5] = a1.y; v[6] = a1.z; v[7] = a1.w;
                } else {
                    #pragma unroll
                    for (int j = 0; j < 8; j++) v[j] = 0.f;
                }
                if (d0 <= 104) {
                    float4 b0 = *(const float4*)(rp + d0);
                    float4 b1 = *(const float4*)(rp + d0 + 4);
                    v[8]  = b0.x; v[9]  = b0.y; v[10] = b0.z; v[11] = b0.w;
                    v[12] = b1.x; v[13] = b1.y; v[14] = b1.z; v[15] = b1.w;
                } else {
                    #pragma unroll
                    for (int j = 8; j < 16; j++) v[j] = 0.f;
                }
                if (d0 <= 96) {
                    float4 c0 = *(const float4*)(rp + d0 + 8);
                    float4 c1 = *(const float4*)(rp + d0 + 12);
                    v[16] = c0.x; v[17] = c0.y; v[18] = c0.z; v[19] = c0.w;
                    v[20] = c1.x; v[21] = c1.y; v[22] = c1.z; v[23] = c1.w;
                } else {
                    #pragma unroll
                    for (int j = 16; j < 24; j++) v[j] = 0.f;
                }
                #pragma unroll
                for (int k = 0; k < 16; k++) acc[k] += v[k + 5] + v[k + 6] + v[k + 7];
            }
        }

    unsigned short ch[16];
    #pragma unroll
    for (int k = 0; k < 16; k++) { bf16 bb = f2b(acc[k]); ch[k] = *(unsigned short*)&bb; }
    uint2* dst = (uint2*)((unsigned short*)pf + (size_t)c * NPF + (size_t)(a * PW + b) * PT + d0);
    int nst = (d0 == 112) ? 1 : 4;
    #pragma unroll
    for (int k = 0; k < 4; k++) if (k < nst) dst[k] = ((uint2*)ch)[k];
}

// ===== FUSED corr + assemble (BIG path) =====
__global__ __launch_bounds__(256) void corr_assemble_kernel(const bf16* __restrict__ pm,
                                                            const bf16* __restrict__ pf,
                                                            const bf16* __restrict__ xw,
                                                            const float* __restrict__ y,
                                                            bf16* __restrict__ stack)
{
    int v = blockIdx.x * 256 + threadIdx.x;
    if (v >= N) return;
    int t = v % T; int hw = v / T; int w = hw % W; int h = hw / W;

    float pmv[16];
    #pragma unroll
    for (int c = 0; c < 16; c++) pmv[c] = b2f(pm[(size_t)c * N + v]);

    float acc[27];
    #pragma unroll
    for (int i = 0; i < 27; i++) acc[i] = 0.f;

    const size_t pbase = ((size_t)h * PW + w) * PT + t;
    #pragma unroll 1
    for (int c = 0; c < 16; c++) {
        const bf16* pfc = pf + (size_t)c * NPF + pbase;
        float pv = pmv[c];
        #pragma unroll
        for (int i = 0; i < 3; i++)
            #pragma unroll
            for (int j = 0; j < 3; j++)
                #pragma unroll
                for (int k = 0; k < 3; k++)
                    acc[i * 9 + j * 3 + k] += pv * b2f(pfc[((size_t)(2 * i) * PW + 2 * j) * PT + 2 * k]);
    }

    unsigned short ch[64];
    #pragma unroll
    for (int c = 0; c < 16; c++) ch[c] = ((const unsigned short*)xw)[(size_t)c * N + v];
    #pragma unroll
    for (int i = 0; i < 27; i++) { bf16 b = f2b(acc[i] * (1.f / 27.f)); ch[16 + i] = *(unsigned short*)&b; }
    #pragma unroll
    for (int c = 0; c < 16; c++) { bf16 b = f2b(y[(size_t)c * N + v]); ch[43 + c] = *(unsigned short*)&b; }
    #pragma unroll
    for (int c = 59; c < 64; c++) ch[c] = 0;
    uint4* dst = (uint4*)((unsigned short*)stack + (size_t)v * 64);
    #pragma unroll
    for (int k = 0; k < 8; k++) dst[k] = ((uint4*)ch)[k];
}

// ---- old two-kernel corr/assemble (SMALL fallback path only) ----
__global__ __launch_bounds__(256) void corr_kernel(const bf16* __restrict__ pm, const bf16* __restrict__ pf,
                                                   bf16* __restrict__ corr_tmp)
{
    int v = blockIdx.x * 256 + threadIdx.x;
    if (v >= N) return;
    int t = v % T; int hw = v / T; int w = hw % W; int h = hw / W;
    float pmv[16];
    #pragma unroll
    for (int c = 0; c < 16; c++) pmv[c] = b2f(pm[(size_t)c * N + v]);
    #pragma unroll 1
    for (int i = 0; i < 3; i++)
    #pragma unroll 1
    for (int j = 0; j < 3; j++)
    #pragma unroll 1
    for (int k = 0; k < 3; k++) {
        size_t base = ((size_t)(2 * i + h) * PW + (2 * j + w)) * PT + (2 * k + t);
        float s = 0.f;
        #pragma unroll
        for (int c = 0; c < 16; c++) s += pmv[c] * b2f(pf[(size_t)c * NPF + base]);
        corr_tmp[(size_t)v * 28 + (i * 9 + j * 3 + k)] = f2b(s * (1.f / 27.f));
    }
}

__global__ __launch_bounds__(256) void assemble_kernel(const bf16* __restrict__ xw,
                                                       const bf16* __restrict__ corr_tmp,
                                                       const float* __restrict__ y,
                                                       bf16* __restrict__ stack)
{
    int v = blockIdx.x * 256 + threadIdx.x;
    if (v >= N) return;
    unsigned short ch[64];
    #pragma unroll
    for (int c = 0; c < 16; c++) ch[c] = ((const unsigned short*)xw)[(size_t)c * N + v];
    #pragma unroll
    for (int i = 0; i < 27; i++) ch[16 + i] = ((const unsigned short*)corr_tmp)[(size_t)v * 28 + i];
    #pragma unroll
    for (int c = 0; c < 16; c++) { bf16 b = f2b(y[(size_t)c * N + v]); ch[43 + c] = *(unsigned short*)&b; }
    #pragma unroll
    for (int c = 59; c < 64; c++) ch[c] = 0;
    uint4* dst = (uint4*)((unsigned short*)stack + (size_t)v * 64);
    #pragma unroll
    for (int k = 0; k < 8; k++) dst[k] = ((uint4*)ch)[k];
}

// ================= MFMA implicit-GEMM conv, LDS A-halo, FULL tap unroll =================
// Base pointer abase = smem + (wv*108+n16)*80 + q*16; per-(tap,m2) LDS offset is a
// compile-time immediate after unrolling -> interior path has zero VALU per A-read.
template <int CST_IN, int KC_TOT, int NT, int NT_TOT, int CST_OUT, bool RELU, int STORE>
__global__ __launch_bounds__(256, 3) void conv_lds(const bf16* __restrict__ in,
                                                   const bf16* __restrict__ wb,
                                                   const float* __restrict__ bias,
                                                   const bf16* __restrict__ aux,
                                                   void* __restrict__ out,
                                                   int kc_off, int nt_off)
{
    constexpr int KCP     = CST_IN / 32;
    constexpr int ASTRIDE = 80;
    constexpr int ZOFF    = 648 * ASTRIDE;
    __shared__ __align__(16) char smem[648 * ASTRIDE + 16];

    const int tid  = threadIdx.x;
    const int lane = tid & 63;
    const int n16  = lane & 15;
    const int q    = lane >> 4;
    const int wv   = tid >> 6;

    int bid = blockIdx.x;
    int cid = (bid & 7) * 420 + (bid >> 3);
    int t0  = (cid % 7) * 16;
    int rs  = cid / 7;
    int w0  = (rs % 24) * 4;
    int h0  = (rs / 24) * 4;
    const int h = h0 + wv;

    const bool interior = (h0 != 0) && (h0 != H - 4) && (w0 != 0) && (w0 != W - 4)
                       && (t0 != 0) && (t0 != T - 16);

    f32x4 acc[4][NT];
    #pragma unroll
    for (int nt = 0; nt < NT; ++nt) {
        float bv = (STORE == 1) ? 0.f : bias[nt * 16 + n16];
        #pragma unroll
        for (int m2 = 0; m2 < 4; ++m2)
            #pragma unroll
            for (int r = 0; r < 4; ++r) acc[m2][nt][r] = bv;
    }

    if (tid < 4) *(int*)(smem + ZOFF + tid * 4) = 0;

    const char* abase = smem + (size_t)(wv * 108 + n16) * ASTRIDE + q * 16;

    auto run = [&](auto chk_c) {
        constexpr bool CHK = decltype(chk_c)::value;
        unsigned msk[4];
        if (CHK) {
            #pragma unroll
            for (int m2 = 0; m2 < 4; ++m2) {
                int w = w0 + m2, t = t0 + n16;
                bool vh[3] = { h > 0, true, h < H - 1 };
                bool vw[3] = { w > 0, true, w < W - 1 };
                bool vt[3] = { t > 0, true, t < T - 1 };
                unsigned m = 0;
                #pragma unroll
                for (int tap = 0; tap < 27; ++tap)
                    if (vh[tap / 9] && vw[(tap % 9) / 3] && vt[tap % 3]) m |= (1u << tap);
                msk[m2] = m;
            }
        }

        #pragma unroll 1
        for (int kcp = 0; kcp < KCP; ++kcp) {
            if (kcp > 0) __syncthreads();
            #pragma unroll 1
            for (int it = 0; it < 11; ++it) {
                int slot = it * 64 + (tid >> 2);
                if (slot < 648) {
                    int hh = slot / 108, rm = slot - hh * 108;
                    int ww = rm / 18,    tt = rm - ww * 18;
                    int gh = min(max(h0 - 1 + hh, 0), H - 1);
                    int gw = min(max(w0 - 1 + ww, 0), W - 1);
                    int gt = min(max(t0 - 1 + tt, 0), T - 1);
                    const char* gp = (const char*)in + (size_t)((gh * W + gw) * T + gt) * (CST_IN * 2)
                                     + kcp * 64 + (tid & 3) * 16;
                    *(uint4*)(smem + slot * ASTRIDE + (tid & 3) * 16) = *(const uint4*)gp;
                }
            }
            __syncthreads();

            const char* wbk = (const char*)wb
                            + ((size_t)(kcp + kc_off) * NT_TOT + nt_off) * 1024
                            + (size_t)lane * 16;

            #pragma unroll
            for (int tap = 0; tap < 27; ++tap) {
                short8 bv[NT];
                #pragma unroll
                for (int nt = 0; nt < NT; ++nt)
                    bv[nt] = *(const short8*)(wbk + (size_t)tap * (KC_TOT * NT_TOT * 1024) + nt * 1024);

                int dh = tap / 9, rr = tap - dh * 9, dw = rr / 3, dt = rr - dw * 3;
                short8 av[4];
                #pragma unroll
                for (int m2 = 0; m2 < 4; ++m2) {
                    int boff = ((dh * 6 + m2 + dw) * 18 + dt) * ASTRIDE;   // compile-time after unroll
                    const char* p;
                    if (CHK) {
                        bool ok = (msk[m2] >> tap) & 1u;
                        p = ok ? (abase + boff) : (smem + ZOFF);
                    } else {
                        p = abase + boff;
                    }
                    av[m2] = *(const short8*)p;
                }
                #pragma unroll
                for (int nt = 0; nt < NT; ++nt)
                    #pragma unroll
                    for (int m2 = 0; m2 < 4; ++m2)
                        acc[m2][nt] = __builtin_amdgcn_mfma_f32_16x16x32_bf16(av[m2], bv[nt], acc[m2][nt], 0, 0, 0);
            }
        }
    };
    if (interior) run(std::integral_constant<bool, false>{});
    else          run(std::integral_constant<bool, true>{});

    #pragma unroll
    for (int m2 = 0; m2 < 4; ++m2) {
        int vrow = (h * W + (w0 + m2)) * T + t0 + q * 4;
        #pragma unroll
        for (int r = 0; r < 4; ++r) {
            int v = vrow + r;
            #pragma unroll
            for (int nt = 0; nt < NT; ++nt) {
                float x = acc[m2][nt][r];
                if (STORE == 2 && nt == 0) x += b2f(aux[(size_t)v * 16 + n16]);
                if (RELU && STORE != 4) x = fmaxf(x, 0.f);
                if (STORE == 4) x = fmaxf(x, 0.f) + b2f(aux[(size_t)v * CST_OUT + nt * 16 + n16]);
                if (STORE == 1) {
                    if (nt == 0) ((bf16*)out)[(size_t)v * 16 + n16] = f2b(x);
                } else if (STORE == 3) {
                    int ch = nt * 16 + n16;
                    if (ch < 3) ((float*)out)[(size_t)ch * N + v] = x;
                } else {
                    ((bf16*)out)[(size_t)v * CST_OUT + nt * 16 + n16] = f2b(x);
                }
            }
        }
    }
}

extern "C" void kernel_launch(void* const* d_in, const int* in_sizes, int n_in,
                              void* d_out, int out_size, void* d_ws, size_t ws_size,
                              hipStream_t stream)
{
    (void)in_sizes; (void)n_in; (void)out_size;
    const float* x_p   = (const float*)d_in[0];
    const float* y_p   = (const float*)d_in[1];
    const float* flow_p= (const float*)d_in[2];
    const float* w1a_p = (const float*)d_in[3];
    const float* b1a_p = (const float*)d_in[4];
    const float* w1b_p = (const float*)d_in[5];
    const float* b1b_p = (const float*)d_in[6];
    const float* w2a_p = (const float*)d_in[7];
    const float* b2a_p = (const float*)d_in[8];
    const float* w2b_p = (const float*)d_in[9];
    const float* b2b_p = (const float*)d_in[10];
    const float* wf_p  = (const float*)d_in[11];
    const float* bf_p  = (const float*)d_in[12];

    char* wsb = (char*)d_ws;
    const size_t NB32 = (size_t)N * 32 * 2;          // 55,050,240
    const size_t NB64 = 2 * NB32;                    // 110,100,480
    const size_t WSUM = (110592 + 55296 + 27648 + 27648 + 13824);
    const size_t NEED_BIG = 2 * NB64 + WSUM * 2 + 176 * 4 + 256;  // 220,671,936
    const bool BIG = (ws_size >= NEED_BIG);

    bf16 *stack, *buf1, *pm, *pf, *xw, *corr_tmp, *hbuf, *t2buf, *sumbuf, *hpart, *buf1h;
    float* flow_up; bf16* wroot;
    if (BIG) {
        stack    = (bf16*)wsb;
        flow_up  = (float*)wsb;
        hbuf     = (bf16*)wsb;
        t2buf    = (bf16*)(wsb + NB32);
        buf1     = (bf16*)(wsb + NB64);
        xw       = (bf16*)(wsb + NB64);
        pm       = (bf16*)(wsb + NB64 + (size_t)16 * N * 2);
        pf       = (bf16*)(wsb + NB64 + (size_t)32 * N * 2);
        sumbuf   = (bf16*)(wsb + NB64);
        corr_tmp = nullptr; hpart = nullptr; buf1h = nullptr;
        wroot    = (bf16*)(wsb + 2 * NB64);
    } else {
        const size_t A_off = 0, B_off = 2 * NB32, C_off = 3 * NB32;
        const size_t D_off = C_off + (size_t)N * 16 * 2;
        pf       = (bf16*)(wsb + A_off);
        pm       = (bf16*)(wsb + A_off + (size_t)16 * NPF * 2);
        flow_up  = (float*)(wsb + A_off + (size_t)16 * NPF * 2 + (size_t)16 * N * 2);
        stack    = (bf16*)(wsb + A_off);
        hbuf     = (bf16*)(wsb + A_off);
        t2buf    = (bf16*)(wsb + A_off + NB32);
        corr_tmp = (bf16*)(wsb + B_off);
        buf1h    = (bf16*)(wsb + B_off);
        sumbuf   = (bf16*)(wsb + B_off);
        xw       = (bf16*)(wsb + C_off);
        hpart    = (bf16*)(wsb + C_off);
        buf1     = nullptr;
        wroot    = (bf16*)(wsb + D_off);
    }
    bf16*  wb1a  = wroot;
    bf16*  wb1b  = wb1a + 110592;
    bf16*  wb2a  = wb1b + 55296;
    bf16*  wb2b  = wb2a + 27648;
    bf16*  wbf   = wb2b + 27648;
    float* biasp = (float*)(wbf + 13824);

    wbuild_kernel<<<432, 256, 0, stream>>>(w1a_p, wb1a, 59, 59, 2, 4);
    wbuild_kernel<<<216, 256, 0, stream>>>(w1b_p, wb1b, 16, 59, 2, 2);
    wbuild_kernel<<<108, 256, 0, stream>>>(w2a_p, wb2a, 16, 16, 1, 2);
    wbuild_kernel<<<108, 256, 0, stream>>>(w2b_p, wb2b, 16, 16, 1, 2);
    wbuild_kernel<<<54,  256, 0, stream>>>(wf_p,  wbf,  3,  16, 1, 1);
    bias_kernel<<<1, 256, 0, stream>>>(b1a_p, b1b_p, b2a_p, b2b_p, bf_p, biasp);

    upsample_kernel<<<3 * N / 256, 256, 0, stream>>>(flow_p, flow_up);
    warp_kernel<<<N / 256, 256, 0, stream>>>(x_p, flow_up, xw);
    pm_kernel<<<N / 256, 256, 0, stream>>>(xw, pm);
    pf_kernel<<<16 * PH * PW * 8 / 256, 256, 0, stream>>>(y_p, pf);
    if (BIG) {
        corr_assemble_kernel<<<N / 256, 256, 0, stream>>>(pm, pf, xw, y_p, stack);
    } else {
        corr_kernel<<<N / 256, 256, 0, stream>>>(pm, pf, corr_tmp);
        assemble_kernel<<<N / 256, 256, 0, stream>>>(xw, corr_tmp, y_p, stack);
    }

    const int GB = N / 256;  // 3360 brick blocks
    if (BIG) {
        conv_lds<64, 2, 4, 4, 64, false, 0><<<GB, 256, 0, stream>>>(stack, wb1a, biasp + 0,   nullptr, buf1,  0, 0);
        conv_lds<64, 2, 2, 2, 32, true,  0><<<GB, 256, 0, stream>>>(buf1,  wb1b, biasp + 64,  nullptr, hbuf,  0, 0);
    } else {
        conv_lds<64, 2, 2, 4, 32, false, 0><<<GB, 256, 0, stream>>>(stack, wb1a, biasp + 0,   nullptr, buf1h, 0, 0);
        conv_lds<32, 2, 2, 2, 32, false, 1><<<GB, 256, 0, stream>>>(buf1h, wb1b, biasp,       nullptr, hpart, 0, 0);
        conv_lds<64, 2, 2, 4, 32, false, 0><<<GB, 256, 0, stream>>>(stack, wb1a, biasp + 32,  nullptr, buf1h, 0, 2);
        conv_lds<32, 2, 2, 2, 32, true,  2><<<GB, 256, 0, stream>>>(buf1h, wb1b, biasp + 64,  hpart,   hbuf,  1, 0);
    }
    conv_lds<32, 1, 2, 2, 32, false, 0><<<GB, 256, 0, stream>>>(hbuf,  wb2a, biasp + 96,  nullptr, t2buf,  0, 0);
    conv_lds<32, 1, 2, 2, 32, false, 4><<<GB, 256, 0, stream>>>(t2buf, wb2b, biasp + 128, hbuf,    sumbuf, 0, 0);
    conv_lds<32, 1, 1, 1, 16, false, 3><<<GB, 256, 0, stream>>>(sumbuf, wbf, biasp + 160, nullptr, d_out,  0, 0);
}

// Round 11
// 979.631 us; speedup vs baseline: 1.2175x; 1.2175x over previous
//
#include <hip/hip_runtime.h>
#include <hip/hip_bf16.h>
#include <cstddef>
#include <type_traits>

typedef __hip_bfloat16 bf16;
typedef __attribute__((ext_vector_type(8))) short short8;   // 8 bf16 = one MFMA A/B frag
typedef __attribute__((ext_vector_type(4))) float f32x4;    // MFMA 16x16 accumulator

constexpr int H = 80, W = 96, T = 112;
constexpr int N = H * W * T;               // 860160
constexpr int WT = W * T;                  // 10752
constexpr int Hh = 40, Wh = 48, Th = 56;
constexpr int Nh = Hh * Wh * Th;
constexpr int PH = 84, PW = 100, PT = 116;
constexpr int NPF = PH * PW * PT;          // 974400

static __device__ __forceinline__ float b2f(bf16 v) { return __bfloat162float(v); }
static __device__ __forceinline__ bf16  f2b(float v) { return __float2bfloat16(v); }
static __device__ __forceinline__ float us2f(unsigned short u) { return __uint_as_float(((unsigned)u) << 16); }

// ================= weight build: w[COUT][CIN][27] f32 -> frag-order bf16 =================
__global__ __launch_bounds__(256) void wbuild_kernel(const float* __restrict__ w, bf16* __restrict__ wb,
                                                     int COUT, int CIN, int KC_TOT, int NT_TOT)
{
    int idx = blockIdx.x * 256 + threadIdx.x;
    int total = 27 * KC_TOT * NT_TOT * 512;
    if (idx >= total) return;
    int j    = idx & 7;
    int lane = (idx >> 3) & 63;
    int rest = idx >> 9;
    int nt   = rest % NT_TOT; rest /= NT_TOT;
    int kc   = rest % KC_TOT;
    int tap  = rest / KC_TOT;
    int o    = nt * 16 + (lane & 15);
    int cin  = kc * 32 + (lane >> 4) * 8 + j;
    float val = (o < COUT && cin < CIN) ? w[((size_t)o * CIN + cin) * 27 + tap] : 0.f;
    wb[idx] = f2b(val);
}

// ---- padded biases: [0,64) b1a | [64,96) b1b | [96,128) b2a | [128,160) b2b | [160,176) bf
__global__ __launch_bounds__(256) void bias_kernel(const float* __restrict__ b1a, const float* __restrict__ b1b,
                                                   const float* __restrict__ b2a, const float* __restrict__ b2b,
                                                   const float* __restrict__ bff, float* __restrict__ out)
{
    int i = threadIdx.x;
    if (i < 64)       out[i] = (i < 59) ? b1a[i] : 0.f;
    else if (i < 96)  { int j = i - 64;  out[i] = (j < 16) ? b1b[j] : 0.f; }
    else if (i < 128) { int j = i - 96;  out[i] = (j < 16) ? b2a[j] : 0.f; }
    else if (i < 160) { int j = i - 128; out[i] = (j < 16) ? b2b[j] : 0.f; }
    else if (i < 176) { int j = i - 160; out[i] = (j < 3)  ? bff[j] : 0.f; }
}

// ================= pre-conv pipeline =================
__global__ __launch_bounds__(256) void upsample_kernel(const float* __restrict__ flow,
                                                       float* __restrict__ flow_up)
{
    int idx = blockIdx.x * 256 + threadIdx.x;
    if (idx >= 3 * N) return;
    int c = idx / N, v = idx % N;
    int t = v % T; int hw = v / T; int w = hw % W; int h = hw / W;
    float ph = (float)h * ((float)(Hh - 1) / (float)(H - 1));
    float pw = (float)w * ((float)(Wh - 1) / (float)(W - 1));
    float pt = (float)t * ((float)(Th - 1) / (float)(T - 1));
    int i0 = min((int)ph, Hh - 2); float fh = ph - (float)i0;
    int j0 = min((int)pw, Wh - 2); float fw = pw - (float)j0;
    int k0 = min((int)pt, Th - 2); float ft = pt - (float)k0;
    const float* fp = flow + (size_t)c * Nh;
    auto L = [&](int a, int b, int d) -> float {
        return 2.0f * fp[((size_t)a * Wh + b) * Th + d];
    };
    float v000 = L(i0, j0, k0),     v001 = L(i0, j0, k0 + 1);
    float v010 = L(i0, j0 + 1, k0), v011 = L(i0, j0 + 1, k0 + 1);
    float v100 = L(i0 + 1, j0, k0),     v101 = L(i0 + 1, j0, k0 + 1);
    float v110 = L(i0 + 1, j0 + 1, k0), v111 = L(i0 + 1, j0 + 1, k0 + 1);
    float val = (1.f - fh) * ((1.f - fw) * ((1.f - ft) * v000 + ft * v001)
                            +        fw  * ((1.f - ft) * v010 + ft * v011))
              +        fh  * ((1.f - fw) * ((1.f - ft) * v100 + ft * v101)
                            +        fw  * ((1.f - ft) * v110 + ft * v111));
    flow_up[idx] = val;
}

// warp -> xw planar bf16 [16][N]
__global__ __launch_bounds__(256) void warp_kernel(const float* __restrict__ x,
                                                   const float* __restrict__ flow_up,
                                                   bf16* __restrict__ xw)
{
    int v = blockIdx.x * 256 + threadIdx.x;
    if (v >= N) return;
    int t = v % T; int hw = v / T; int w = hw % W; int h = hw / W;
    float cx = (float)h + flow_up[v];
    float cy = (float)w + flow_up[N + v];
    float cz = (float)t + flow_up[2 * N + v];
    float fx0 = floorf(cx), fy0 = floorf(cy), fz0 = floorf(cz);
    float fx = cx - fx0, fy = cy - fy0, fz = cz - fz0;
    int ix = (int)fx0, iy = (int)fy0, iz = (int)fz0;

    float wc[8];
    int   oc[8];
    #pragma unroll
    for (int c8 = 0; c8 < 8; c8++) {
        int dx = (c8 >> 2) & 1, dy = (c8 >> 1) & 1, dz = c8 & 1;
        int ax = ix + dx, ay = iy + dy, az = iz + dz;
        bool ok = ((unsigned)ax < (unsigned)H) && ((unsigned)ay < (unsigned)W) && ((unsigned)az < (unsigned)T);
        float wt = (dx ? fx : 1.f - fx) * (dy ? fy : 1.f - fy) * (dz ? fz : 1.f - fz);
        wc[c8] = ok ? wt : 0.f;
        int cax = min(max(ax, 0), H - 1);
        int cay = min(max(ay, 0), W - 1);
        int caz = min(max(az, 0), T - 1);
        oc[c8] = (cax * W + cay) * T + caz;
    }
    #pragma unroll 1
    for (int c = 0; c < 16; c++) {
        const float* xp = x + (size_t)c * N;
        float s = 0.f;
        #pragma unroll
        for (int c8 = 0; c8 < 8; c8++) s += wc[c8] * xp[oc[c8]];
        xw[(size_t)c * N + v] = f2b(s);
    }
}

// ===== pm = box3(xw, pad=1), strip-vectorized: 1 thread = 16 t-outputs =====
__global__ __launch_bounds__(256) void pm_kernel(const bf16* __restrict__ xw, bf16* __restrict__ pm)
{
    int idx = blockIdx.x * 256 + threadIdx.x;
    int ts = idx % 7;  int r = idx / 7;
    int w  = r % W;    r /= W;
    int h  = r % H;    int c = r / H;
    int t0 = ts * 16;

    float acc[16];
    #pragma unroll
    for (int k = 0; k < 16; k++) acc[k] = 0.f;

    const bf16* base = xw + (size_t)c * N;
    #pragma unroll
    for (int dh = -1; dh <= 1; dh++)
        #pragma unroll
        for (int dw = -1; dw <= 1; dw++) {
            int hh = h + dh, ww = w + dw;
            if (((unsigned)hh < (unsigned)H) && ((unsigned)ww < (unsigned)W)) {
                const unsigned short* rp = (const unsigned short*)(base + (size_t)(hh * W + ww) * T);
                float v[18];
                v[0] = (t0 > 0) ? us2f(rp[t0 - 1]) : 0.f;
                short8 cA = *(const short8*)(rp + t0);
                short8 cB = *(const short8*)(rp + t0 + 8);
                #pragma unroll
                for (int j = 0; j < 8; j++) v[1 + j] = us2f((unsigned short)cA[j]);
                #pragma unroll
                for (int j = 0; j < 8; j++) v[9 + j] = us2f((unsigned short)cB[j]);
                v[17] = (t0 + 16 < T) ? us2f(rp[t0 + 16]) : 0.f;
                #pragma unroll
                for (int k = 0; k < 16; k++) acc[k] += v[k] + v[k + 1] + v[k + 2];
            }
        }

    unsigned short ch[16];
    #pragma unroll
    for (int k = 0; k < 16; k++) { bf16 b = f2b(acc[k]); ch[k] = *(unsigned short*)&b; }
    uint4* dst = (uint4*)((unsigned short*)pm + (size_t)c * N + (size_t)(h * W + w) * T + t0);
    dst[0] = ((uint4*)ch)[0];
    dst[1] = ((uint4*)ch)[1];
}

// ===== pf = box3(y, pad=3), strip-vectorized: 1 thread = 16 d-outputs =====
__global__ __launch_bounds__(256) void pf_kernel(const float* __restrict__ y, bf16* __restrict__ pf)
{
    int idx = blockIdx.x * 256 + threadIdx.x;
    int ds = idx & 7;  int r = idx >> 3;
    int b  = r % PW;   r /= PW;
    int a  = r % PH;   int c = r / PH;
    int d0 = ds * 16;

    float acc[16];
    #pragma unroll
    for (int k = 0; k < 16; k++) acc[k] = 0.f;

    const float* base = y + (size_t)c * N;
    #pragma unroll
    for (int da = 0; da < 3; da++)
        #pragma unroll
        for (int db = 0; db < 3; db++) {
            int hh = a - 3 + da, ww = b - 3 + db;
            if (((unsigned)hh < (unsigned)H) && ((unsigned)ww < (unsigned)W)) {
                const float* rp = base + (size_t)(hh * W + ww) * T;
                float v[24];
                if (d0 >= 8) {
                    float4 a0 = *(const float4*)(rp + d0 - 8);
                    float4 a1 = *(const float4*)(rp + d0 - 4);
                    v[0] = a0.x; v[1] = a0.y; v[2] = a0.z; v[3] = a0.w;
                    v[4] = a1.x; v[5] = a1.y; v[6] = a1.z; v[7] = a1.w;
                } else {
                    #pragma unroll
                    for (int j = 0; j < 8; j++) v[j] = 0.f;
                }
                if (d0 <= 104) {
                    float4 b0 = *(const float4*)(rp + d0);
                    float4 b1 = *(const float4*)(rp + d0 + 4);
                    v[8]  = b0.x; v[9]  = b0.y; v[10] = b0.z; v[11] = b0.w;
                    v[12] = b1.x; v[13] = b1.y; v[14] = b1.z; v[15] = b1.w;
                } else {
                    #pragma unroll
                    for (int j = 8; j < 16; j++) v[j] = 0.f;
                }
                if (d0 <= 96) {
                    float4 c0 = *(const float4*)(rp + d0 + 8);
                    float4 c1 = *(const float4*)(rp + d0 + 12);
                    v[16] = c0.x; v[17] = c0.y; v[18] = c0.z; v[19] = c0.w;
                    v[20] = c1.x; v[21] = c1.y; v[22] = c1.z; v[23] = c1.w;
                } else {
                    #pragma unroll
                    for (int j = 16; j < 24; j++) v[j] = 0.f;
                }
                #pragma unroll
                for (int k = 0; k < 16; k++) acc[k] += v[k + 5] + v[k + 6] + v[k + 7];
            }
        }

    unsigned short ch[16];
    #pragma unroll
    for (int k = 0; k < 16; k++) { bf16 bb = f2b(acc[k]); ch[k] = *(unsigned short*)&bb; }
    uint2* dst = (uint2*)((unsigned short*)pf + (size_t)c * NPF + (size_t)(a * PW + b) * PT + d0);
    int nst = (d0 == 112) ? 1 : 4;
    #pragma unroll
    for (int k = 0; k < 4; k++) if (k < nst) dst[k] = ((uint2*)ch)[k];
}

// ===== FUSED corr + assemble (BIG path) =====
__global__ __launch_bounds__(256) void corr_assemble_kernel(const bf16* __restrict__ pm,
                                                            const bf16* __restrict__ pf,
                                                            const bf16* __restrict__ xw,
                                                            const float* __restrict__ y,
                                                            bf16* __restrict__ stack)
{
    int v = blockIdx.x * 256 + threadIdx.x;
    if (v >= N) return;
    int t = v % T; int hw = v / T; int w = hw % W; int h = hw / W;

    float pmv[16];
    #pragma unroll
    for (int c = 0; c < 16; c++) pmv[c] = b2f(pm[(size_t)c * N + v]);

    float acc[27];
    #pragma unroll
    for (int i = 0; i < 27; i++) acc[i] = 0.f;

    const size_t pbase = ((size_t)h * PW + w) * PT + t;
    #pragma unroll 1
    for (int c = 0; c < 16; c++) {
        const bf16* pfc = pf + (size_t)c * NPF + pbase;
        float pv = pmv[c];
        #pragma unroll
        for (int i = 0; i < 3; i++)
            #pragma unroll
            for (int j = 0; j < 3; j++)
                #pragma unroll
                for (int k = 0; k < 3; k++)
                    acc[i * 9 + j * 3 + k] += pv * b2f(pfc[((size_t)(2 * i) * PW + 2 * j) * PT + 2 * k]);
    }

    unsigned short ch[64];
    #pragma unroll
    for (int c = 0; c < 16; c++) ch[c] = ((const unsigned short*)xw)[(size_t)c * N + v];
    #pragma unroll
    for (int i = 0; i < 27; i++) { bf16 b = f2b(acc[i] * (1.f / 27.f)); ch[16 + i] = *(unsigned short*)&b; }
    #pragma unroll
    for (int c = 0; c < 16; c++) { bf16 b = f2b(y[(size_t)c * N + v]); ch[43 + c] = *(unsigned short*)&b; }
    #pragma unroll
    for (int c = 59; c < 64; c++) ch[c] = 0;
    uint4* dst = (uint4*)((unsigned short*)stack + (size_t)v * 64);
    #pragma unroll
    for (int k = 0; k < 8; k++) dst[k] = ((uint4*)ch)[k];
}

// ---- old two-kernel corr/assemble (SMALL fallback path only) ----
__global__ __launch_bounds__(256) void corr_kernel(const bf16* __restrict__ pm, const bf16* __restrict__ pf,
                                                   bf16* __restrict__ corr_tmp)
{
    int v = blockIdx.x * 256 + threadIdx.x;
    if (v >= N) return;
    int t = v % T; int hw = v / T; int w = hw % W; int h = hw / W;
    float pmv[16];
    #pragma unroll
    for (int c = 0; c < 16; c++) pmv[c] = b2f(pm[(size_t)c * N + v]);
    #pragma unroll 1
    for (int i = 0; i < 3; i++)
    #pragma unroll 1
    for (int j = 0; j < 3; j++)
    #pragma unroll 1
    for (int k = 0; k < 3; k++) {
        size_t base = ((size_t)(2 * i + h) * PW + (2 * j + w)) * PT + (2 * k + t);
        float s = 0.f;
        #pragma unroll
        for (int c = 0; c < 16; c++) s += pmv[c] * b2f(pf[(size_t)c * NPF + base]);
        corr_tmp[(size_t)v * 28 + (i * 9 + j * 3 + k)] = f2b(s * (1.f / 27.f));
    }
}

__global__ __launch_bounds__(256) void assemble_kernel(const bf16* __restrict__ xw,
                                                       const bf16* __restrict__ corr_tmp,
                                                       const float* __restrict__ y,
                                                       bf16* __restrict__ stack)
{
    int v = blockIdx.x * 256 + threadIdx.x;
    if (v >= N) return;
    unsigned short ch[64];
    #pragma unroll
    for (int c = 0; c < 16; c++) ch[c] = ((const unsigned short*)xw)[(size_t)c * N + v];
    #pragma unroll
    for (int i = 0; i < 27; i++) ch[16 + i] = ((const unsigned short*)corr_tmp)[(size_t)v * 28 + i];
    #pragma unroll
    for (int c = 0; c < 16; c++) { bf16 b = f2b(y[(size_t)c * N + v]); ch[43 + c] = *(unsigned short*)&b; }
    #pragma unroll
    for (int c = 59; c < 64; c++) ch[c] = 0;
    uint4* dst = (uint4*)((unsigned short*)stack + (size_t)v * 64);
    #pragma unroll
    for (int k = 0; k < 8; k++) dst[k] = ((uint4*)ch)[k];
}

// ================= MFMA implicit-GEMM conv, LDS A-halo, 3-tap groups =================
// Separable halo addressing: arow[m2] = smem + ((wv*6+m2)*18+n16)*80 + q*16 (once);
// per-(dh,dw) group: rowoff += {1440|5760} scalar adds; dt in {0,1,2} unrolled -> ds_read
// offset immediates. No divisions in the hot loop; 3-tap window keeps regs under the
// (256,3) budget (r10's 27-tap unroll spilled).
template <int CST_IN, int KC_TOT, int NT, int NT_TOT, int CST_OUT, bool RELU, int STORE>
__global__ __launch_bounds__(256, 3) void conv_lds(const bf16* __restrict__ in,
                                                   const bf16* __restrict__ wb,
                                                   const float* __restrict__ bias,
                                                   const bf16* __restrict__ aux,
                                                   void* __restrict__ out,
                                                   int kc_off, int nt_off)
{
    constexpr int KCP     = CST_IN / 32;
    constexpr int ASTRIDE = 80;
    constexpr int ZOFF    = 648 * ASTRIDE;
    __shared__ __align__(16) char smem[648 * ASTRIDE + 16];

    const int tid  = threadIdx.x;
    const int lane = tid & 63;
    const int n16  = lane & 15;
    const int q    = lane >> 4;
    const int wv   = tid >> 6;

    int bid = blockIdx.x;
    int cid = (bid & 7) * 420 + (bid >> 3);
    int t0  = (cid % 7) * 16;
    int rs  = cid / 7;
    int w0  = (rs % 24) * 4;
    int h0  = (rs / 24) * 4;
    const int h = h0 + wv;

    const bool interior = (h0 != 0) && (h0 != H - 4) && (w0 != 0) && (w0 != W - 4)
                       && (t0 != 0) && (t0 != T - 16);

    f32x4 acc[4][NT];
    #pragma unroll
    for (int nt = 0; nt < NT; ++nt) {
        float bv = (STORE == 1) ? 0.f : bias[nt * 16 + n16];
        #pragma unroll
        for (int m2 = 0; m2 < 4; ++m2)
            #pragma unroll
            for (int r = 0; r < 4; ++r) acc[m2][nt][r] = bv;
    }

    if (tid < 4) *(int*)(smem + ZOFF + tid * 4) = 0;

    const char* arow[4];
    #pragma unroll
    for (int m2 = 0; m2 < 4; ++m2)
        arow[m2] = smem + (size_t)(((wv * 6 + m2) * 18 + n16) * ASTRIDE) + q * 16;

    auto run = [&](auto chk_c) {
        constexpr bool CHK = decltype(chk_c)::value;
        unsigned msk[4];
        if (CHK) {
            #pragma unroll
            for (int m2 = 0; m2 < 4; ++m2) {
                int w = w0 + m2, t = t0 + n16;
                bool vh[3] = { h > 0, true, h < H - 1 };
                bool vw[3] = { w > 0, true, w < W - 1 };
                bool vt[3] = { t > 0, true, t < T - 1 };
                unsigned m = 0;
                #pragma unroll
                for (int tap = 0; tap < 27; ++tap)
                    if (vh[tap / 9] && vw[(tap % 9) / 3] && vt[tap % 3]) m |= (1u << tap);
                msk[m2] = m;
            }
        }

        #pragma unroll 1
        for (int kcp = 0; kcp < KCP; ++kcp) {
            if (kcp > 0) __syncthreads();
            #pragma unroll 1
            for (int it = 0; it < 11; ++it) {
                int slot = it * 64 + (tid >> 2);
                if (slot < 648) {
                    int hh = slot / 108, rm = slot - hh * 108;
                    int ww = rm / 18,    tt = rm - ww * 18;
                    int gh = min(max(h0 - 1 + hh, 0), H - 1);
                    int gw = min(max(w0 - 1 + ww, 0), W - 1);
                    int gt = min(max(t0 - 1 + tt, 0), T - 1);
                    const char* gp = (const char*)in + (size_t)((gh * W + gw) * T + gt) * (CST_IN * 2)
                                     + kcp * 64 + (tid & 3) * 16;
                    *(uint4*)(smem + slot * ASTRIDE + (tid & 3) * 16) = *(const uint4*)gp;
                }
            }
            __syncthreads();

            const size_t TAPB = (size_t)KC_TOT * NT_TOT * 1024;
            const char* wbt = (const char*)wb
                            + ((size_t)(kcp + kc_off) * NT_TOT + nt_off) * 1024
                            + (size_t)lane * 16;
            int rowoff = 0, c3 = 0, tshift = 0;

            #pragma unroll 1
            for (int g = 0; g < 9; ++g) {
                short8 bv[3][NT];
                #pragma unroll
                for (int dt = 0; dt < 3; ++dt)
                    #pragma unroll
                    for (int nt = 0; nt < NT; ++nt)
                        bv[dt][nt] = *(const short8*)(wbt + dt * TAPB + nt * 1024);

                short8 av[3][4];
                #pragma unroll
                for (int m2 = 0; m2 < 4; ++m2) {
                    const char* p = arow[m2] + rowoff;
                    #pragma unroll
                    for (int dt = 0; dt < 3; ++dt) {
                        const char* q2;
                        if (CHK) {
                            bool ok = (msk[m2] >> (tshift + dt)) & 1u;
                            q2 = ok ? (p + dt * ASTRIDE) : (smem + ZOFF);
                        } else {
                            q2 = p + dt * ASTRIDE;
                        }
                        av[dt][m2] = *(const short8*)q2;
                    }
                }

                #pragma unroll
                for (int dt = 0; dt < 3; ++dt)
                    #pragma unroll
                    for (int nt = 0; nt < NT; ++nt)
                        #pragma unroll
                        for (int m2 = 0; m2 < 4; ++m2)
                            acc[m2][nt] = __builtin_amdgcn_mfma_f32_16x16x32_bf16(av[dt][m2], bv[dt][nt], acc[m2][nt], 0, 0, 0);

                wbt += 3 * TAPB;
                tshift += 3;
                if (c3 == 2) { rowoff += 4 * 1440; c3 = 0; }
                else         { rowoff += 1440;     c3++;   }
            }
        }
    };
    if (interior) run(std::integral_constant<bool, false>{});
    else          run(std::integral_constant<bool, true>{});

    #pragma unroll
    for (int m2 = 0; m2 < 4; ++m2) {
        int vrow = (h * W + (w0 + m2)) * T + t0 + q * 4;
        #pragma unroll
        for (int r = 0; r < 4; ++r) {
            int v = vrow + r;
            #pragma unroll
            for (int nt = 0; nt < NT; ++nt) {
                float x = acc[m2][nt][r];
                if (STORE == 2 && nt == 0) x += b2f(aux[(size_t)v * 16 + n16]);
                if (RELU && STORE != 4) x = fmaxf(x, 0.f);
                if (STORE == 4) x = fmaxf(x, 0.f) + b2f(aux[(size_t)v * CST_OUT + nt * 16 + n16]);
                if (STORE == 1) {
                    if (nt == 0) ((bf16*)out)[(size_t)v * 16 + n16] = f2b(x);
                } else if (STORE == 3) {
                    int ch = nt * 16 + n16;
                    if (ch < 3) ((float*)out)[(size_t)ch * N + v] = x;
                } else {
                    ((bf16*)out)[(size_t)v * CST_OUT + nt * 16 + n16] = f2b(x);
                }
            }
        }
    }
}

extern "C" void kernel_launch(void* const* d_in, const int* in_sizes, int n_in,
                              void* d_out, int out_size, void* d_ws, size_t ws_size,
                              hipStream_t stream)
{
    (void)in_sizes; (void)n_in; (void)out_size;
    const float* x_p   = (const float*)d_in[0];
    const float* y_p   = (const float*)d_in[1];
    const float* flow_p= (const float*)d_in[2];
    const float* w1a_p = (const float*)d_in[3];
    const float* b1a_p = (const float*)d_in[4];
    const float* w1b_p = (const float*)d_in[5];
    const float* b1b_p = (const float*)d_in[6];
    const float* w2a_p = (const float*)d_in[7];
    const float* b2a_p = (const float*)d_in[8];
    const float* w2b_p = (const float*)d_in[9];
    const float* b2b_p = (const float*)d_in[10];
    const float* wf_p  = (const float*)d_in[11];
    const float* bf_p  = (const float*)d_in[12];

    char* wsb = (char*)d_ws;
    const size_t NB32 = (size_t)N * 32 * 2;          // 55,050,240
    const size_t NB64 = 2 * NB32;                    // 110,100,480
    const size_t WSUM = (110592 + 55296 + 27648 + 27648 + 13824);
    const size_t NEED_BIG = 2 * NB64 + WSUM * 2 + 176 * 4 + 256;  // 220,671,936
    const bool BIG = (ws_size >= NEED_BIG);

    bf16 *stack, *buf1, *pm, *pf, *xw, *corr_tmp, *hbuf, *t2buf, *sumbuf, *hpart, *buf1h;
    float* flow_up; bf16* wroot;
    if (BIG) {
        stack    = (bf16*)wsb;
        flow_up  = (float*)wsb;
        hbuf     = (bf16*)wsb;
        t2buf    = (bf16*)(wsb + NB32);
        buf1     = (bf16*)(wsb + NB64);
        xw       = (bf16*)(wsb + NB64);
        pm       = (bf16*)(wsb + NB64 + (size_t)16 * N * 2);
        pf       = (bf16*)(wsb + NB64 + (size_t)32 * N * 2);
        sumbuf   = (bf16*)(wsb + NB64);
        corr_tmp = nullptr; hpart = nullptr; buf1h = nullptr;
        wroot    = (bf16*)(wsb + 2 * NB64);
    } else {
        const size_t A_off = 0, B_off = 2 * NB32, C_off = 3 * NB32;
        const size_t D_off = C_off + (size_t)N * 16 * 2;
        pf       = (bf16*)(wsb + A_off);
        pm       = (bf16*)(wsb + A_off + (size_t)16 * NPF * 2);
        flow_up  = (float*)(wsb + A_off + (size_t)16 * NPF * 2 + (size_t)16 * N * 2);
        stack    = (bf16*)(wsb + A_off);
        hbuf     = (bf16*)(wsb + A_off);
        t2buf    = (bf16*)(wsb + A_off + NB32);
        corr_tmp = (bf16*)(wsb + B_off);
        buf1h    = (bf16*)(wsb + B_off);
        sumbuf   = (bf16*)(wsb + B_off);
        xw       = (bf16*)(wsb + C_off);
        hpart    = (bf16*)(wsb + C_off);
        buf1     = nullptr;
        wroot    = (bf16*)(wsb + D_off);
    }
    bf16*  wb1a  = wroot;
    bf16*  wb1b  = wb1a + 110592;
    bf16*  wb2a  = wb1b + 55296;
    bf16*  wb2b  = wb2a + 27648;
    bf16*  wbf   = wb2b + 27648;
    float* biasp = (float*)(wbf + 13824);

    wbuild_kernel<<<432, 256, 0, stream>>>(w1a_p, wb1a, 59, 59, 2, 4);
    wbuild_kernel<<<216, 256, 0, stream>>>(w1b_p, wb1b, 16, 59, 2, 2);
    wbuild_kernel<<<108, 256, 0, stream>>>(w2a_p, wb2a, 16, 16, 1, 2);
    wbuild_kernel<<<108, 256, 0, stream>>>(w2b_p, wb2b, 16, 16, 1, 2);
    wbuild_kernel<<<54,  256, 0, stream>>>(wf_p,  wbf,  3,  16, 1, 1);
    bias_kernel<<<1, 256, 0, stream>>>(b1a_p, b1b_p, b2a_p, b2b_p, bf_p, biasp);

    upsample_kernel<<<3 * N / 256, 256, 0, stream>>>(flow_p, flow_up);
    warp_kernel<<<N / 256, 256, 0, stream>>>(x_p, flow_up, xw);
    pm_kernel<<<N / 256, 256, 0, stream>>>(xw, pm);
    pf_kernel<<<16 * PH * PW * 8 / 256, 256, 0, stream>>>(y_p, pf);
    if (BIG) {
        corr_assemble_kernel<<<N / 256, 256, 0, stream>>>(pm, pf, xw, y_p, stack);
    } else {
        corr_kernel<<<N / 256, 256, 0, stream>>>(pm, pf, corr_tmp);
        assemble_kernel<<<N / 256, 256, 0, stream>>>(xw, corr_tmp, y_p, stack);
    }

    const int GB = N / 256;  // 3360 brick blocks
    if (BIG) {
        conv_lds<64, 2, 4, 4, 64, false, 0><<<GB, 256, 0, stream>>>(stack, wb1a, biasp + 0,   nullptr, buf1,  0, 0);
        conv_lds<64, 2, 2, 2, 32, true,  0><<<GB, 256, 0, stream>>>(buf1,  wb1b, biasp + 64,  nullptr, hbuf,  0, 0);
    } else {
        conv_lds<64, 2, 2, 4, 32, false, 0><<<GB, 256, 0, stream>>>(stack, wb1a, biasp + 0,   nullptr, buf1h, 0, 0);
        conv_lds<32, 2, 2, 2, 32, false, 1><<<GB, 256, 0, stream>>>(buf1h, wb1b, biasp,       nullptr, hpart, 0, 0);
        conv_lds<64, 2, 2, 4, 32, false, 0><<<GB, 256, 0, stream>>>(stack, wb1a, biasp + 32,  nullptr, buf1h, 0, 2);
        conv_lds<32, 2, 2, 2, 32, true,  2><<<GB, 256, 0, stream>>>(buf1h, wb1b, biasp + 64,  hpart,   hbuf,  1, 0);
    }
    conv_lds<32, 1, 2, 2, 32, false, 0><<<GB, 256, 0, stream>>>(hbuf,  wb2a, biasp + 96,  nullptr, t2buf,  0, 0);
    conv_lds<32, 1, 2, 2, 32, false, 4><<<GB, 256, 0, stream>>>(t2buf, wb2b, biasp + 128, hbuf,    sumbuf, 0, 0);
    conv_lds<32, 1, 1, 1, 16, false, 3><<<GB, 256, 0, stream>>>(sumbuf, wbf, biasp + 160, nullptr, d_out,  0, 0);
}